// Round 14
// baseline (226.334 us; speedup 1.0000x reference)
//
#include <hip/hip_runtime.h>

#define S_LEN 4096
#define NROWS 16384          // B*S

typedef float f32x4 __attribute__((ext_vector_type(4)));
typedef _Float16 f16x8 __attribute__((ext_vector_type(8)));

__device__ __forceinline__ unsigned short f2h(float f) {
  _Float16 h = (_Float16)f;
  return __builtin_bit_cast(unsigned short, h);
}

__device__ __forceinline__ void gload16(const void* g, void* l) {
  __builtin_amdgcn_global_load_lds(
      (const __attribute__((address_space(1))) void*)g,
      (__attribute__((address_space(3))) void*)l, 16, 0, 0);
}

// ---------------- weight convert (fp32 -> fp16) ----------------
__global__ void cw_kernel(const float* __restrict__ Wq, const float* __restrict__ Wk,
                          unsigned short* __restrict__ Wqb, unsigned short* __restrict__ Wkb) {
  const int i = (blockIdx.x * 256 + threadIdx.x) * 8;
  if (i >= 131072) return;
  unsigned short tmp[8] __attribute__((aligned(16)));
#pragma unroll
  for (int u = 0; u < 8; ++u) tmp[u] = f2h(Wq[i + u]);
  *(uint4*)(Wqb + i) = ((const uint4*)tmp)[0];
#pragma unroll
  for (int u = 0; u < 8; ++u) tmp[u] = f2h(Wk[i + u]);
  *(uint4*)(Wkb + i) = ((const uint4*)tmp)[0];
}

// ---------------- V transpose: [B][S][D] f32 -> [B][D][S] fp16 ----------------
__global__ __launch_bounds__(256) void vt_kernel(const float* __restrict__ V,
                                                 unsigned short* __restrict__ Vt) {
  __shared__ float tile[64][65];
  const int tid = threadIdx.x;
  const int b = blockIdx.z, s0 = blockIdx.x * 64, d0 = blockIdx.y * 64;
  {
    const int r = tid >> 2, cs = (tid & 3) * 16;
    const float* src = V + ((long)b * S_LEN + s0 + r) * 256 + d0 + cs;
#pragma unroll
    for (int u = 0; u < 4; ++u) {
      const f32x4 v = __builtin_nontemporal_load((const f32x4*)(src + 4 * u));
      tile[r][cs + 4 * u + 0] = v[0]; tile[r][cs + 4 * u + 1] = v[1];
      tile[r][cs + 4 * u + 2] = v[2]; tile[r][cs + 4 * u + 3] = v[3];
    }
  }
  __syncthreads();
  {
    const int d = tid >> 2, ss = (tid & 3) * 16;
    unsigned short tmp[16] __attribute__((aligned(16)));
#pragma unroll
    for (int u = 0; u < 16; ++u) tmp[u] = f2h(tile[ss + u][d]);
    unsigned short* dst = Vt + ((long)b * 256 + d0 + d) * S_LEN + s0 + ss;
    *(uint4*)dst = ((const uint4*)tmp)[0];
    *((uint4*)dst + 1) = ((const uint4*)tmp)[1];
  }
}

// ---------------- projection GEMM: out = fp16((X[16384x512] * W^T[512x256] + b) * sc) --------
// sc for Q = scale_factor * log2(e): folds BOTH attention scaling and the exp->exp2
// conversion into Q. K uses sc = 1.
__global__ __launch_bounds__(256, 4) void proj_kernel(
    const float* __restrict__ Xq, const float* __restrict__ Xk,
    const unsigned short* __restrict__ Wqb, const unsigned short* __restrict__ Wkb,
    const float* __restrict__ bq, const float* __restrict__ bk,
    unsigned short* __restrict__ Qb, unsigned short* __restrict__ Kb,
    const float* __restrict__ scale_ptr) {
  const int tid = threadIdx.x;
  const int lane = tid & 63, w = tid >> 6;
  const int h = lane >> 4, cc = lane & 15;
  const int z = blockIdx.y;
  const float* X = z ? Xk : Xq;
  const unsigned short* Wb = z ? Wkb : Wqb;
  const float* bias = z ? bk : bq;
  unsigned short* out = z ? Kb : Qb;
  const float sc = z ? 1.f : scale_ptr[0] * 1.44269504088896340736f;
  const int rowbase = blockIdx.x * 64;

  __shared__ char sx[8192];    // X tile [64][64] fp16, swizzled
  __shared__ char sw[32768];   // W tile [256][64] fp16, swizzled

  f32x4 acc[16];
  const f32x4 fz = {0.f, 0.f, 0.f, 0.f};
#pragma unroll
  for (int nf = 0; nf < 16; ++nf) acc[nf] = fz;

  for (int kstep = 0; kstep < 8; ++kstep) {
    const int k0 = kstep * 64;
    __syncthreads();  // previous compute reads done before overwrite
    {  // X stage: fp32 nt-load -> fp16 -> swizzled ds_write_b128
      const int r = tid >> 2;
      const int cb0 = (tid & 3) * 2;
      const float* src = X + (long)(rowbase + r) * 512 + k0 + (tid & 3) * 16;
      float xv[16];
#pragma unroll
      for (int u = 0; u < 4; ++u) {
        const f32x4 v = __builtin_nontemporal_load((const f32x4*)(src + 4 * u));
        xv[4 * u + 0] = v[0]; xv[4 * u + 1] = v[1];
        xv[4 * u + 2] = v[2]; xv[4 * u + 3] = v[3];
      }
      unsigned short tmp[16] __attribute__((aligned(16)));
#pragma unroll
      for (int u = 0; u < 16; ++u) tmp[u] = f2h(xv[u]);
      *(uint4*)(sx + r * 128 + ((cb0 ^ (r & 7)) * 16)) = ((const uint4*)tmp)[0];
      *(uint4*)(sx + r * 128 + (((cb0 + 1) ^ (r & 7)) * 16)) = ((const uint4*)tmp)[1];
    }
    // W stage: global_load_lds, linear LDS dest + inverse-swizzled global source
#pragma unroll
    for (int i = 0; i < 8; ++i) {
      const int off = w * 8192 + i * 1024 + lane * 16;
      const int row = off >> 7;
      const int lcb = (lane & 7) ^ (row & 7);
      gload16(Wb + (long)row * 512 + k0 + lcb * 8, sw + w * 8192 + i * 1024);
    }
    __syncthreads();
#pragma unroll
    for (int ks = 0; ks < 2; ++ks) {
      const int rl = 16 * w + cc;
      const f16x8 af = *(const f16x8*)(sx + rl * 128 + (((h + 4 * ks) ^ (rl & 7)) * 16));
#pragma unroll
      for (int nf = 0; nf < 16; ++nf) {
        const int n = cc + 16 * nf;
        const f16x8 bf = *(const f16x8*)(sw + n * 128 + (((h + 4 * ks) ^ (n & 7)) * 16));
        acc[nf] = __builtin_amdgcn_mfma_f32_16x16x32_f16(af, bf, acc[nf], 0, 0, 0);
      }
    }
  }
#pragma unroll
  for (int nf = 0; nf < 16; ++nf) {
    const float bv = bias[cc + 16 * nf];
#pragma unroll
    for (int r = 0; r < 4; ++r) {
      const long grow = rowbase + 16 * w + 4 * h + r;
      out[grow * 256 + cc + 16 * nf] = f2h((acc[nf][r] + bv) * sc);
    }
  }
}

// ---------------- flash attention v3: d-split wave pairs ----------------
// 256-thread block = 2 pairs x 2 waves; pair p owns q-rows qrow0+p*32..+32.
// Wave kvh = w&1: QK^T over kv-half (16 kv, m-rep 2 over 32 q) and PV over
// d-half (O[32q][128d] = 64 acc regs). LDS-per-wave-iter: K 8K + V 8K + P ~3K
// = 19 KB vs r13's 33 KB (1.74x) at identical MFMA count -- this is m-rep=2
// with the accumulator split across the pair, dodging r9's register wall.
// Softmax m is SHARED within the pair: okbit/lmax exchanged via LDS with
// raw lgkmcnt(0)+s_barrier pairs (LDS-only protocol); the vmem staging keeps
// the proven __syncthreads full drain at iter end (r10 lesson).
// Scores are in log2 domain (log2e folded into Q); exp2f throughout.
// LDS: K 2x16K @0, V 2x16K @32768, P 2x2560 @65536, comm 512 @70656,
// okbits @71168, claim @71184 => 71200 B => 2 blocks/CU.
__global__ __launch_bounds__(256, 2) void attn_kernel(
    const unsigned short* __restrict__ Qb, const unsigned short* __restrict__ Kb,
    const unsigned short* __restrict__ Vt, float* __restrict__ out0,
    float* __restrict__ partials, float2* __restrict__ stats,
    int* __restrict__ cnt, int nsplit, int nchunks) {
  extern __shared__ char smem[];
  const int tid = threadIdx.x;
  const int lane = tid & 63, w = tid >> 6;
  const int h = lane >> 4, c = lane & 15;
  const int p = w >> 1, kvh = w & 1;

  // ---- claim a work item from this XCD's chunk (exactly-once: tickets <32) ----
  int* s_item_p = (int*)(smem + 71184);
  if (tid == 0) {
    const unsigned x = __builtin_amdgcn_s_getreg(6164) & 7u;  // HW_REG_XCC_ID(20),off0,sz4
    const int pref = (int)x * nchunks / 8;
    int item = 0;
    for (int k = 0; k < nchunks; ++k) {
      const int ch = (pref + k) % nchunks;
      const int t = atomicAdd(cnt + ch, 1);
      if (t < 32) { item = ch * 32 + t; break; }
    }
    *s_item_p = item;
  }
  __syncthreads();
  const int nid = *s_item_p;
  const int gqt = nid & 255;      // q-tile among 256 (BQ=64)
  const int split = nid >> 8;

  const int b = gqt >> 6;
  const int qrow0 = (gqt & 63) * 64;
  const long brow = (long)b * S_LEN;

  const int kv_len = S_LEN / nsplit;
  const int kv0 = split * kv_len;
  const int nit = kv_len / 32;

  // Q fragments: pair's 32 q-rows, m-rep 2 x 8 k-steps (scale*log2e pre-folded)
  f16x8 qf[2][8];
  {
    const unsigned short* qbase = Qb + (brow + qrow0 + p * 32 + c) * 256 + h * 8;
#pragma unroll
    for (int m = 0; m < 2; ++m)
#pragma unroll
      for (int kk = 0; kk < 8; ++kk)
        qf[m][kk] = *(const f16x8*)(qbase + m * 4096 + kk * 32);
  }

  f32x4 O[2][8];                 // [m][nfd]: q=16m+4h+r, d = kvh*128 + c + 16*nfd
  float mrun[2][4], lrun[2][4];  // mrun SHARED within pair by construction
  const f32x4 fz = {0.f, 0.f, 0.f, 0.f};
#pragma unroll
  for (int m = 0; m < 2; ++m) {
#pragma unroll
    for (int nfd = 0; nfd < 8; ++nfd) O[m][nfd] = fz;
#pragma unroll
    for (int r = 0; r < 4; ++r) { mrun[m][r] = -1e30f; lrun[m][r] = 0.f; }
  }

  const unsigned short* kbB = Kb + brow * 256;
  const unsigned short* vbB = Vt + (long)b * 256 * S_LEN;

  auto stage = [&](int buf, int it) {
    const int kvb = kv0 + it * 32;
#pragma unroll
    for (int i = 0; i < 4; ++i) {
      const int off = i * 4096 + tid * 16;
      {  // K tile [32][256] fp16, rows 512B; inverse-swizzled source
        const int row = off >> 9;
        const int lcb = ((off >> 4) & 31) ^ (row & 7);
        gload16(kbB + (long)(kvb + row) * 256 + lcb * 8, smem + buf * 16384 + off);
      }
      {  // V tile [256][32] fp16, rows 64B; inverse-swizzled source
        const int drow = off >> 6;
        const int lcb = ((off >> 4) & 3) ^ ((drow >> 1) & 3);
        gload16(vbB + (long)drow * S_LEN + kvb + lcb * 8,
                smem + 32768 + buf * 16384 + off);
      }
    }
  };

  char* const ppt = smem + 65536 + p * 2560;          // pair P [32 q][80 B rows]
  float* const comm = (float*)(smem + 70656 + p * 256);  // [kvh][32 q] f32
  int* const okb = (int*)(smem + 71168);

  stage(0, 0);
  __syncthreads();

  for (int t = 0; t < nit; ++t) {
    const int buf = t & 1;
    if (t + 1 < nit) stage(buf ^ 1, t + 1);   // prefetch into other buffer
    const char* kt = smem + buf * 16384;
    const char* vl = smem + 32768 + buf * 16384;

    // ---- QK^T: 32 q (m-rep 2) x 16 kv (this wave's half) ----
    f32x4 s[2];
    s[0] = fz; s[1] = fz;
    __builtin_amdgcn_s_setprio(1);
#pragma unroll
    for (int kk = 0; kk < 8; ++kk) {
      const int krow = kvh * 16 + c;
      const int cb = ((4 * kk + h) ^ (c & 7)) & 31;
      const f16x8 kf = *(const f16x8*)(kt + krow * 512 + cb * 16);
      s[0] = __builtin_amdgcn_mfma_f32_16x16x32_f16(qf[0][kk], kf, s[0], 0, 0, 0);
      s[1] = __builtin_amdgcn_mfma_f32_16x16x32_f16(qf[1][kk], kf, s[1], 0, 0, 0);
    }
    __builtin_amdgcn_s_setprio(0);

    // ---- pair-shared defer-max decision (okbit exchange, LDS-only barrier) ----
    bool ok = true;
#pragma unroll
    for (int m = 0; m < 2; ++m)
#pragma unroll
      for (int r = 0; r < 4; ++r) ok &= (s[m][r] <= mrun[m][r] + 8.f);
    const int okw = __all(ok) ? 1 : 0;
    if (lane == 0) okb[w] = okw;
    asm volatile("s_waitcnt lgkmcnt(0)" ::: "memory");
    __builtin_amdgcn_sched_barrier(0);
    __builtin_amdgcn_s_barrier();                       // B1: okbits ready
    const int blockfast = okb[0] & okb[1] & okb[2] & okb[3];

    if (blockfast) {  // fast path: no reduce, no rescale, mrun unchanged
#pragma unroll
      for (int m = 0; m < 2; ++m)
#pragma unroll
        for (int r = 0; r < 4; ++r) {
          const float pp = exp2f(s[m][r] - mrun[m][r]);
          lrun[m][r] += pp;
          *(unsigned short*)(ppt + (16 * m + 4 * h + r) * 80 + kvh * 32 + c * 2) =
              f2h(pp);
        }
    } else {          // slow path: cross-wave shared max (block-uniform branch)
      float lm[2][4];
#pragma unroll
      for (int m = 0; m < 2; ++m)
#pragma unroll
        for (int r = 0; r < 4; ++r) {
          float mx = s[m][r];
          mx = fmaxf(mx, __shfl_xor(mx, 1));
          mx = fmaxf(mx, __shfl_xor(mx, 2));
          mx = fmaxf(mx, __shfl_xor(mx, 4));
          mx = fmaxf(mx, __shfl_xor(mx, 8));
          lm[m][r] = mx;
        }
      if (c == 0) {
#pragma unroll
        for (int m = 0; m < 2; ++m)
#pragma unroll
          for (int r = 0; r < 4; ++r)
            comm[kvh * 32 + 16 * m + 4 * h + r] = lm[m][r];
      }
      asm volatile("s_waitcnt lgkmcnt(0)" ::: "memory");
      __builtin_amdgcn_sched_barrier(0);
      __builtin_amdgcn_s_barrier();                     // B2x: lmax exchanged
#pragma unroll
      for (int m = 0; m < 2; ++m)
#pragma unroll
        for (int r = 0; r < 4; ++r) {
          const float pmx = comm[(kvh ^ 1) * 32 + 16 * m + 4 * h + r];
          const float mnew = fmaxf(mrun[m][r], fmaxf(lm[m][r], pmx));
          const float alpha = exp2f(mrun[m][r] - mnew);
          const float pp = exp2f(s[m][r] - mnew);
          lrun[m][r] = lrun[m][r] * alpha + pp;
          mrun[m][r] = mnew;
#pragma unroll
          for (int nfd = 0; nfd < 8; ++nfd) O[m][nfd][r] *= alpha;
          *(unsigned short*)(ppt + (16 * m + 4 * h + r) * 80 + kvh * 32 + c * 2) =
              f2h(pp);
        }
    }
    asm volatile("s_waitcnt lgkmcnt(0)" ::: "memory");
    __builtin_amdgcn_sched_barrier(0);
    __builtin_amdgcn_s_barrier();                       // B2: P ready

    // ---- PV: full 32 kv of P x this wave's d-half ----
    __builtin_amdgcn_s_setprio(1);
    {
      f16x8 pa[2];
#pragma unroll
      for (int m = 0; m < 2; ++m)
        pa[m] = *(const f16x8*)(ppt + (16 * m + c) * 80 + h * 16);
#pragma unroll
      for (int nfd = 0; nfd < 8; ++nfd) {
        const int dr = kvh * 128 + c + 16 * nfd;
        const f16x8 vf = *(const f16x8*)(vl + dr * 64 + (((h ^ (dr >> 1)) & 3) * 16));
        O[0][nfd] = __builtin_amdgcn_mfma_f32_16x16x32_f16(pa[0], vf, O[0][nfd], 0, 0, 0);
        O[1][nfd] = __builtin_amdgcn_mfma_f32_16x16x32_f16(pa[1], vf, O[1][nfd], 0, 0, 0);
      }
    }
    __builtin_amdgcn_s_setprio(0);
    __syncthreads();   // B3 full drain: staged loads landed, all buf reads done
  }

  // ---- epilogue: reduce l over the 16-lane kv group, then pair-combine ----
#pragma unroll
  for (int m = 0; m < 2; ++m)
#pragma unroll
    for (int r = 0; r < 4; ++r) {
      float l = lrun[m][r];
      l += __shfl_xor(l, 1); l += __shfl_xor(l, 2);
      l += __shfl_xor(l, 4); l += __shfl_xor(l, 8);
      lrun[m][r] = l;
    }
  if (c == 0) {
#pragma unroll
    for (int m = 0; m < 2; ++m)
#pragma unroll
      for (int r = 0; r < 4; ++r)
        comm[kvh * 32 + 16 * m + 4 * h + r] = lrun[m][r];
  }
  __syncthreads();
  float lt[2][4];
#pragma unroll
  for (int m = 0; m < 2; ++m)
#pragma unroll
    for (int r = 0; r < 4; ++r)
      lt[m][r] = lrun[m][r] + comm[(kvh ^ 1) * 32 + 16 * m + 4 * h + r];

  const long rowg0 = brow + qrow0 + p * 32 + 4 * h;
  if (nsplit == 1) {
#pragma unroll
    for (int m = 0; m < 2; ++m) {
      float inv[4];
#pragma unroll
      for (int r = 0; r < 4; ++r) inv[r] = 1.f / lt[m][r];
#pragma unroll
      for (int nfd = 0; nfd < 8; ++nfd)
#pragma unroll
        for (int r = 0; r < 4; ++r)
          out0[(rowg0 + 16 * m + r) * 256 + kvh * 128 + c + 16 * nfd] =
              O[m][nfd][r] * inv[r];
    }
  } else {
    float* dst = (split == 0) ? out0 : (partials + (long)(split - 1) * NROWS * 256);
#pragma unroll
    for (int m = 0; m < 2; ++m)
#pragma unroll
      for (int nfd = 0; nfd < 8; ++nfd)
#pragma unroll
        for (int r = 0; r < 4; ++r)
          dst[(rowg0 + 16 * m + r) * 256 + kvh * 128 + c + 16 * nfd] = O[m][nfd][r];
    if (kvh == 0 && c == 0) {
#pragma unroll
      for (int m = 0; m < 2; ++m)
#pragma unroll
        for (int r = 0; r < 4; ++r)
          stats[(long)split * NROWS + rowg0 + 16 * m + r] =
              make_float2(mrun[m][r], lt[m][r]);
    }
  }
}

// ---------------- merge KV-split partials (log2-domain stats) ----------------
__global__ __launch_bounds__(256) void merge_kernel(float* __restrict__ out0,
                                                    const float* __restrict__ partials,
                                                    const float2* __restrict__ stats,
                                                    int nsplit) {
  const int i4 = blockIdx.x * 256 + threadIdx.x;  // float4 index, total 1048576
  const int row = i4 >> 6;
  float2 st[4];
#pragma unroll
  for (int s = 0; s < 4; ++s)
    st[s] = (s < nsplit) ? stats[s * NROWS + row] : make_float2(-1e30f, 0.f);
  const float m = fmaxf(fmaxf(st[0].x, st[1].x), fmaxf(st[2].x, st[3].x));
  float e[4], den = 0.f;
#pragma unroll
  for (int s = 0; s < 4; ++s) { e[s] = exp2f(st[s].x - m); den += st[s].y * e[s]; }
  const float invd = 1.f / den;
  float ax = 0.f, ay = 0.f, az = 0.f, aw = 0.f;
#pragma unroll
  for (int s = 0; s < 4; ++s) {
    if (s < nsplit) {
      const float* src = (s == 0) ? (const float*)out0
                                  : partials + (long)(s - 1) * NROWS * 256;
      const f32x4 v = ((const f32x4*)src)[i4];
      ax += v[0] * e[s]; ay += v[1] * e[s]; az += v[2] * e[s]; aw += v[3] * e[s];
    }
  }
  const f32x4 res = {ax * invd, ay * invd, az * invd, aw * invd};
  ((f32x4*)out0)[i4] = res;
}

extern "C" void kernel_launch(void* const* d_in, const int* in_sizes, int n_in,
                              void* d_out, int out_size, void* d_ws, size_t ws_size,
                              hipStream_t stream) {
  const float* query = (const float*)d_in[0];
  const float* key   = (const float*)d_in[1];
  const float* value = (const float*)d_in[2];
  const float* Wq    = (const float*)d_in[3];
  const float* bq    = (const float*)d_in[4];
  const float* Wk    = (const float*)d_in[5];
  const float* bk    = (const float*)d_in[6];
  const float* scale = (const float*)d_in[7];
  float* out = (float*)d_out;

  char* ws = (char*)d_ws;
  unsigned short* Wqb = (unsigned short*)(ws);            // 256 KB
  unsigned short* Wkb = (unsigned short*)(ws + 262144);   // 256 KB
  unsigned short* Qb  = (unsigned short*)(ws + 524288);   // 8 MB
  unsigned short* Kb  = (unsigned short*)(ws + 8912896);  // 8 MB
  unsigned short* Vt  = (unsigned short*)(ws + 17301504); // 8 MB
  int* cnt            = (int*)(ws + 25690112);            // 4 KB
  float2* stats       = (float2*)(ws + 25694208);         // 512 KB
  float* partials     = (float*)(ws + 26218496);          // 16.8 MB at nsplit=2

  int nsplit = 1;
  if (ws_size >= 42995712) nsplit = 2;   // BQ=64: 512 blocks = exactly 2/CU
  const int nblk = 256 * nsplit;
  const int nchunks = nblk / 32;

  hipMemsetAsync(cnt, 0, 64, stream);
  cw_kernel<<<64, 256, 0, stream>>>(Wq, Wk, Wqb, Wkb);
  vt_kernel<<<dim3(64, 4, 4), 256, 0, stream>>>(value, Vt);
  proj_kernel<<<dim3(256, 2), 256, 0, stream>>>(query, key, Wqb, Wkb, bq, bk, Qb, Kb, scale);

  hipFuncSetAttribute((const void*)attn_kernel,
                      hipFuncAttributeMaxDynamicSharedMemorySize, 71200);
  attn_kernel<<<nblk, 256, 71200, stream>>>(Qb, Kb, Vt, out, partials,
                                            stats, cnt, nsplit, nchunks);
  if (nsplit > 1)
    merge_kernel<<<4096, 256, 0, stream>>>(out, partials, stats, nsplit);
}